// Round 5
// baseline (17.697 us; speedup 1.0000x reference)
//
#include <hip/hip_runtime.h>
#include <hip/hip_bf16.h>

// Problem: B=8192, S=8, D=96.
// Math collapses (softmax over axis=1 sums to 1; both einsums are rank-1
// outer products of sequence-sums):
//   out[b,s,d] = sum_e x[b,s,e]*col[e] + pos[s]*W        for ALL d
// where col[e] = sum_n Wv[n,e],  W = sum_e col[e],
//       pos[s] = sum_j j*Wp[s,j] + bp[s].
// Wk, Wq, softmax, and both einsums cancel.
//
// Two graph-ordered kernels:
//   A (1 block): col[96] -> ws[0..95] (as 24 float4), rowadd[8]=pos[s]*W
//      -> ws[96..103]. Parallel coalesced Wv reduce, no serial phase.
//   B (2048 x 256, pure stream): LDS-broadcast col from L2-hot ws (one
//      cheap barrier), then per thread: 3x float4 x-load, 12 FMA,
//      3-level shuffle reduce over the 8-lane row group, + rowadd,
//      3x float4 splat store. Interleaved layout: the 8 lanes of a row
//      take float4s at sub*4 + j*32 -> every access is a full 128B line.

#define NTHR_B 256
#define NBLK_B 2048        // 2048*256 = 524288 chunks = 65536 rows * 8

// ---------------- kernel A: setup into ws ----------------
__global__ __launch_bounds__(1024) void setup_kernel(
    const float* __restrict__ Wp, const float* __restrict__ bp,
    const float* __restrict__ Wv, float* __restrict__ ws) {
    __shared__ __align__(16) float4 part[32][24];   // 12 KB
    __shared__ __align__(16) float4 cols[24];
    __shared__ float posv[8];

    const int t = threadIdx.x;
    const float4* Wv4 = (const float4*)Wv;          // [96 rows][24 slots]
    if (t < 768) {
        const int slot = t % 24;
        const int g    = t / 24;                    // 0..31, 3 rows each
        const int n0   = g * 3;
        float4 s0 = Wv4[(n0 + 0) * 24 + slot];
        float4 s1 = Wv4[(n0 + 1) * 24 + slot];
        float4 s2 = Wv4[(n0 + 2) * 24 + slot];
        part[g][slot] = make_float4(s0.x + s1.x + s2.x, s0.y + s1.y + s2.y,
                                    s0.z + s1.z + s2.z, s0.w + s1.w + s2.w);
    } else if (t < 776) {
        const int s = t - 768;
        float p = bp[s];
        #pragma unroll
        for (int j = 1; j < 8; ++j) p += (float)j * Wp[s * 8 + j];
        posv[s] = p;
    }
    __syncthreads();
    if (t < 24) {
        float4 c = part[0][t];
        #pragma unroll
        for (int g = 1; g < 32; ++g) {
            float4 q = part[g][t];
            c.x += q.x; c.y += q.y; c.z += q.z; c.w += q.w;
        }
        cols[t] = c;
        ((float4*)ws)[t] = c;
    }
    __syncthreads();
    if (t < 8) {
        float W = 0.f;
        #pragma unroll
        for (int k = 0; k < 24; ++k) {
            float4 c = cols[k];
            W += c.x + c.y + c.z + c.w;
        }
        ws[96 + t] = posv[t] * W;
    }
}

// ---------------- kernel B: pure stream ----------------
__global__ __launch_bounds__(NTHR_B) void stream_kernel(
    const float* __restrict__ x, const float* __restrict__ ws,
    float* __restrict__ out) {
    __shared__ __align__(16) float4 col4[24];
    __shared__ float rowadd[8];

    const int t = threadIdx.x;
    const int c = blockIdx.x * NTHR_B + t;
    const int row = c >> 3, sub = c & 7;

    // issue x loads first; latency hides under the LDS fill + barrier
    const float* xb = x + (size_t)row * 96 + sub * 4;
    float4 a0 = *(const float4*)(xb);
    float4 a1 = *(const float4*)(xb + 32);
    float4 a2 = *(const float4*)(xb + 64);

    if (t < 24) col4[t] = ((const float4*)ws)[t];
    else if (t >= 32 && t < 40) rowadd[t - 32] = ws[96 + (t - 32)];
    __syncthreads();

    float4 w0 = col4[sub + 0], w1 = col4[sub + 8], w2 = col4[sub + 16];
    float dot = a0.x * w0.x + a0.y * w0.y + a0.z * w0.z + a0.w * w0.w
              + a1.x * w1.x + a1.y * w1.y + a1.z * w1.z + a1.w * w1.w
              + a2.x * w2.x + a2.y * w2.y + a2.z * w2.z + a2.w * w2.w;
    dot += __shfl_xor(dot, 1);
    dot += __shfl_xor(dot, 2);
    dot += __shfl_xor(dot, 4);
    const float val = dot + rowadd[row & 7];
    float4 v = make_float4(val, val, val, val);
    float* ob = out + (size_t)row * 96 + sub * 4;
    *(float4*)(ob)      = v;
    *(float4*)(ob + 32) = v;
    *(float4*)(ob + 64) = v;
}

extern "C" void kernel_launch(void* const* d_in, const int* in_sizes, int n_in,
                              void* d_out, int out_size, void* d_ws, size_t ws_size,
                              hipStream_t stream) {
    const float* x  = (const float*)d_in[0];
    const float* Wp = (const float*)d_in[1];
    const float* bp = (const float*)d_in[2];
    const float* Wv = (const float*)d_in[3];
    // Wk (d_in[4]) and Wq (d_in[5]) cancel out of the math entirely.
    float* out = (float*)d_out;
    float* ws  = (float*)d_ws;

    setup_kernel<<<1, 1024, 0, stream>>>(Wp, bp, Wv, ws);
    stream_kernel<<<NBLK_B, NTHR_B, 0, stream>>>(x, ws, out);
}

// Round 6
// 13.963 us; speedup vs baseline: 1.2675x; 1.2675x over previous
//
#include <hip/hip_runtime.h>
#include <hip/hip_bf16.h>

// Problem: B=8192, S=8, D=96.
// Math collapses (softmax over axis=1 sums to 1; both einsums are rank-1
// outer products of sequence-sums):
//   out[b,s,d] = sum_e x[b,s,e]*col[e] + pos[s]*W        for ALL d
// where col[e] = sum_n Wv[n,e],  W = sum_e col[e],
//       pos[s] = sum_j j*Wp[s,j] + bp[s].
// Wk, Wq, softmax, and both einsums cancel.
//
// Single fused kernel (R2 structure, best measured): 256 blocks x 1024
// threads, 2 chunks/thread, interleaved fully-coalesced layout. All 6 x
// float4 loads are issued before setup so the whole 25 MB read stream is
// in flight while setup runs. New vs R2: pos is folded into a
// post-reduction scalar rowadd[s] = pos[s]*W (W reduced in-wave with
// shuffles inside the existing reduce step -> still only 2 barriers),
// deleting ~24 VALU adds/thread from the post-barrier hot phase.

#define NTHR 1024
#define NBLK 256          // 256 * 1024 * 2 = 524288 chunks = 65536 rows * 8

__global__ __launch_bounds__(NTHR) void attn_fused_kernel(
    const float* __restrict__ x, const float* __restrict__ Wp,
    const float* __restrict__ bp, const float* __restrict__ Wv,
    float* __restrict__ out) {
    __shared__ __align__(16) float4 part[32][24];   // 12 KB
    __shared__ __align__(16) float4 col4[24];       // col[96]
    __shared__ float posv[8];
    __shared__ float rowadd[8];                     // pos[s]*W

    const int t = threadIdx.x;

    // Block-contiguous chunks: c0 = bid*2048 + t, c1 = c0 + 1024.
    const int c0 = blockIdx.x * (2 * NTHR) + t;
    const int c1 = c0 + NTHR;
    const int row0 = c0 >> 3, sub0 = c0 & 7;
    const int row1 = c1 >> 3, sub1 = c1 & 7;

    // ---- issue ALL x loads FIRST (latency hides under setup) ----
    const float* xb0 = x + (size_t)row0 * 96 + sub0 * 4;
    const float* xb1 = x + (size_t)row1 * 96 + sub1 * 4;
    float4 a0 = *(const float4*)(xb0);
    float4 a1 = *(const float4*)(xb0 + 32);
    float4 a2 = *(const float4*)(xb0 + 64);
    float4 b0 = *(const float4*)(xb1);
    float4 b1 = *(const float4*)(xb1 + 32);
    float4 b2 = *(const float4*)(xb1 + 64);

    // ---- parallel setup: col[e] = sum_n Wv[n,e] ----
    const float4* Wv4 = (const float4*)Wv;          // [96 rows][24 slots]
    if (t < 768) {
        const int slot = t % 24;
        const int g    = t / 24;                    // 0..31, 3 rows each
        const int n0   = g * 3;
        float4 s0 = Wv4[(n0 + 0) * 24 + slot];
        float4 s1 = Wv4[(n0 + 1) * 24 + slot];
        float4 s2 = Wv4[(n0 + 2) * 24 + slot];
        part[g][slot] = make_float4(s0.x + s1.x + s2.x, s0.y + s1.y + s2.y,
                                    s0.z + s1.z + s2.z, s0.w + s1.w + s2.w);
    } else if (t < 776) {
        const int s = t - 768;
        float p = bp[s];
        #pragma unroll
        for (int j = 1; j < 8; ++j) p += (float)j * Wp[s * 8 + j];
        posv[s] = p;
    }
    __syncthreads();
    if (t < 32) {
        float4 cc = make_float4(0.f, 0.f, 0.f, 0.f);
        if (t < 24) {
            cc = part[0][t];
            #pragma unroll
            for (int g = 1; g < 32; ++g) {
                float4 q = part[g][t];
                cc.x += q.x; cc.y += q.y; cc.z += q.z; cc.w += q.w;
            }
            col4[t] = cc;
        }
        // W = sum of all col elements; 32-lane in-wave reduce (lanes 0..31
        // of wave 0, lanes 24..31 contribute 0).
        float w = cc.x + cc.y + cc.z + cc.w;
        w += __shfl_xor(w, 16, 32);
        w += __shfl_xor(w,  8, 32);
        w += __shfl_xor(w,  4, 32);
        w += __shfl_xor(w,  2, 32);
        w += __shfl_xor(w,  1, 32);
        if (t < 8) rowadd[t] = posv[t] * w;
    }
    __syncthreads();

    // ---- chunk 0 ----
    {
        float4 w0 = col4[sub0 + 0], w1 = col4[sub0 + 8], w2 = col4[sub0 + 16];
        float dot = a0.x * w0.x + a0.y * w0.y + a0.z * w0.z + a0.w * w0.w
                  + a1.x * w1.x + a1.y * w1.y + a1.z * w1.z + a1.w * w1.w
                  + a2.x * w2.x + a2.y * w2.y + a2.z * w2.z + a2.w * w2.w;
        dot += __shfl_xor(dot, 1);
        dot += __shfl_xor(dot, 2);
        dot += __shfl_xor(dot, 4);
        const float val = dot + rowadd[row0 & 7];
        float4 v = make_float4(val, val, val, val);
        float* ob = out + (size_t)row0 * 96 + sub0 * 4;
        *(float4*)(ob)      = v;
        *(float4*)(ob + 32) = v;
        *(float4*)(ob + 64) = v;
    }
    // ---- chunk 1 ----
    {
        float4 w0 = col4[sub1 + 0], w1 = col4[sub1 + 8], w2 = col4[sub1 + 16];
        float dot = b0.x * w0.x + b0.y * w0.y + b0.z * w0.z + b0.w * w0.w
                  + b1.x * w1.x + b1.y * w1.y + b1.z * w1.z + b1.w * w1.w
                  + b2.x * w2.x + b2.y * w2.y + b2.z * w2.z + b2.w * w2.w;
        dot += __shfl_xor(dot, 1);
        dot += __shfl_xor(dot, 2);
        dot += __shfl_xor(dot, 4);
        const float val = dot + rowadd[row1 & 7];
        float4 v = make_float4(val, val, val, val);
        float* ob = out + (size_t)row1 * 96 + sub1 * 4;
        *(float4*)(ob)      = v;
        *(float4*)(ob + 32) = v;
        *(float4*)(ob + 64) = v;
    }
}

extern "C" void kernel_launch(void* const* d_in, const int* in_sizes, int n_in,
                              void* d_out, int out_size, void* d_ws, size_t ws_size,
                              hipStream_t stream) {
    const float* x  = (const float*)d_in[0];
    const float* Wp = (const float*)d_in[1];
    const float* bp = (const float*)d_in[2];
    const float* Wv = (const float*)d_in[3];
    // Wk (d_in[4]) and Wq (d_in[5]) cancel out of the math entirely.
    float* out = (float*)d_out;

    attn_fused_kernel<<<NBLK, NTHR, 0, stream>>>(x, Wp, bp, Wv, out);
}

// Round 7
// 13.323 us; speedup vs baseline: 1.3283x; 1.0480x over previous
//
#include <hip/hip_runtime.h>
#include <hip/hip_bf16.h>

// Problem: B=8192, S=8, D=96.
// Math collapses (softmax over axis=1 sums to 1; both einsums are rank-1
// outer products of sequence-sums):
//   out[b,s,d] = sum_e x[b,s,e]*col[e] + pos[s]*W        for ALL d
// where col[e] = sum_n Wv[n,e],  W = sum_e col[e],
//       pos[s] = sum_j j*Wp[s,j] + bp[s].
// Wk, Wq, softmax, and both einsums cancel.
//
// Single fused kernel: 1024 blocks x 256 threads, 2 chunks/thread
// (6 prefetched float4 x-loads per thread -- R2's winning ILP), but now
// 4 blocks/CU so other blocks stream while one sits at its (4-wave,
// cheap) setup barriers. Setup per 256-thr block: 192 threads sum 12
// Wv rows each (coalesced float4, L2-hot), 8-iteration LDS reduce,
// pos folded into rowadd[s] = pos[s]*W via in-wave shuffle reduce.
// Interleaved layout: the 8 lanes of a row take float4s at sub*4+j*32,
// so every 8-lane access is one full 128B line.

#define NTHR 256
#define NBLK 1024         // 1024 * 256 * 2 = 524288 chunks = 65536 rows * 8

__global__ __launch_bounds__(NTHR) void attn_fused_kernel(
    const float* __restrict__ x, const float* __restrict__ Wp,
    const float* __restrict__ bp, const float* __restrict__ Wv,
    float* __restrict__ out) {
    __shared__ __align__(16) float4 part[8][24];    // 3 KB
    __shared__ __align__(16) float4 col4[24];       // col[96]
    __shared__ float posv[8];
    __shared__ float rowadd[8];                     // pos[s]*W

    const int t = threadIdx.x;

    // Block-contiguous chunks: c0 = bid*512 + t, c1 = c0 + 256.
    const int c0 = blockIdx.x * (2 * NTHR) + t;
    const int c1 = c0 + NTHR;
    const int row0 = c0 >> 3, sub0 = c0 & 7;
    const int row1 = c1 >> 3, sub1 = c1 & 7;

    // ---- issue ALL x loads FIRST (latency hides under setup) ----
    const float* xb0 = x + (size_t)row0 * 96 + sub0 * 4;
    const float* xb1 = x + (size_t)row1 * 96 + sub1 * 4;
    float4 a0 = *(const float4*)(xb0);
    float4 a1 = *(const float4*)(xb0 + 32);
    float4 a2 = *(const float4*)(xb0 + 64);
    float4 b0 = *(const float4*)(xb1);
    float4 b1 = *(const float4*)(xb1 + 32);
    float4 b2 = *(const float4*)(xb1 + 64);

    // ---- parallel setup: col[e] = sum_n Wv[n,e] ----
    const float4* Wv4 = (const float4*)Wv;          // [96 rows][24 slots]
    if (t < 192) {
        const int slot = t % 24;
        const int g    = t / 24;                    // 0..7, 12 rows each
        const int n0   = g * 12;
        float4 s = Wv4[n0 * 24 + slot];
        #pragma unroll
        for (int n = 1; n < 12; ++n) {
            float4 q = Wv4[(n0 + n) * 24 + slot];
            s.x += q.x; s.y += q.y; s.z += q.z; s.w += q.w;
        }
        part[g][slot] = s;
    } else if (t < 200) {
        const int s = t - 192;
        float p = bp[s];
        #pragma unroll
        for (int j = 1; j < 8; ++j) p += (float)j * Wp[s * 8 + j];
        posv[s] = p;
    }
    __syncthreads();
    if (t < 32) {
        float4 cc = make_float4(0.f, 0.f, 0.f, 0.f);
        if (t < 24) {
            cc = part[0][t];
            #pragma unroll
            for (int g = 1; g < 8; ++g) {
                float4 q = part[g][t];
                cc.x += q.x; cc.y += q.y; cc.z += q.z; cc.w += q.w;
            }
            col4[t] = cc;
        }
        // W = sum of all col elements; in-wave 32-lane reduce
        // (lanes 24..31 contribute 0).
        float w = cc.x + cc.y + cc.z + cc.w;
        w += __shfl_xor(w, 16, 32);
        w += __shfl_xor(w,  8, 32);
        w += __shfl_xor(w,  4, 32);
        w += __shfl_xor(w,  2, 32);
        w += __shfl_xor(w,  1, 32);
        if (t < 8) rowadd[t] = posv[t] * w;
    }
    __syncthreads();

    // ---- chunk 0 ----
    {
        float4 w0 = col4[sub0 + 0], w1 = col4[sub0 + 8], w2 = col4[sub0 + 16];
        float dot = a0.x * w0.x + a0.y * w0.y + a0.z * w0.z + a0.w * w0.w
                  + a1.x * w1.x + a1.y * w1.y + a1.z * w1.z + a1.w * w1.w
                  + a2.x * w2.x + a2.y * w2.y + a2.z * w2.z + a2.w * w2.w;
        dot += __shfl_xor(dot, 1);
        dot += __shfl_xor(dot, 2);
        dot += __shfl_xor(dot, 4);
        const float val = dot + rowadd[row0 & 7];
        float4 v = make_float4(val, val, val, val);
        float* ob = out + (size_t)row0 * 96 + sub0 * 4;
        *(float4*)(ob)      = v;
        *(float4*)(ob + 32) = v;
        *(float4*)(ob + 64) = v;
    }
    // ---- chunk 1 ----
    {
        float4 w0 = col4[sub1 + 0], w1 = col4[sub1 + 8], w2 = col4[sub1 + 16];
        float dot = b0.x * w0.x + b0.y * w0.y + b0.z * w0.z + b0.w * w0.w
                  + b1.x * w1.x + b1.y * w1.y + b1.z * w1.z + b1.w * w1.w
                  + b2.x * w2.x + b2.y * w2.y + b2.z * w2.z + b2.w * w2.w;
        dot += __shfl_xor(dot, 1);
        dot += __shfl_xor(dot, 2);
        dot += __shfl_xor(dot, 4);
        const float val = dot + rowadd[row1 & 7];
        float4 v = make_float4(val, val, val, val);
        float* ob = out + (size_t)row1 * 96 + sub1 * 4;
        *(float4*)(ob)      = v;
        *(float4*)(ob + 32) = v;
        *(float4*)(ob + 64) = v;
    }
}

extern "C" void kernel_launch(void* const* d_in, const int* in_sizes, int n_in,
                              void* d_out, int out_size, void* d_ws, size_t ws_size,
                              hipStream_t stream) {
    const float* x  = (const float*)d_in[0];
    const float* Wp = (const float*)d_in[1];
    const float* bp = (const float*)d_in[2];
    const float* Wv = (const float*)d_in[3];
    // Wk (d_in[4]) and Wq (d_in[5]) cancel out of the math entirely.
    float* out = (float*)d_out;

    attn_fused_kernel<<<NBLK, NTHR, 0, stream>>>(x, Wp, bp, Wv, out);
}

// Round 8
// 13.193 us; speedup vs baseline: 1.3414x; 1.0098x over previous
//
#include <hip/hip_runtime.h>
#include <hip/hip_bf16.h>

// Problem: B=8192, S=8, D=96.
// Math collapses (softmax over axis=1 sums to 1; both einsums are rank-1
// outer products of sequence-sums):
//   out[b,s,d] = sum_e x[b,s,e]*col[e] + pos[s]*W        for ALL d
// where col[e] = sum_n Wv[n,e],  W = sum_e col[e],
//       pos[s] = sum_j j*Wp[s,j] + bp[s].
// Wk, Wq, softmax, and both einsums cancel.
//
// Single fused kernel: 512 blocks x 256 threads, 4 chunks/thread
// (12 prefetched float4 x-loads per thread -> deep per-thread MLP in the
// read burst), 2 blocks/CU, cheap 4-wave barriers. Setup per block: 192
// threads sum 12 Wv rows each (coalesced float4, L2/L3-hot after first
// replay), 8-iter LDS reduce, pos folded into rowadd[s] = pos[s]*W via
// in-wave shuffle. Interleaved layout: the 8 lanes of a row take float4s
// at sub*4 + j*32, so every 8-lane access is one full 128B line.

#define NTHR 256
#define NBLK 512          // 512 * 256 * 4 = 524288 chunks = 65536 rows * 8

__global__ __launch_bounds__(NTHR) void attn_fused_kernel(
    const float* __restrict__ x, const float* __restrict__ Wp,
    const float* __restrict__ bp, const float* __restrict__ Wv,
    float* __restrict__ out) {
    __shared__ __align__(16) float4 part[8][24];    // 3 KB
    __shared__ __align__(16) float4 col4[24];       // col[96]
    __shared__ float posv[8];
    __shared__ float rowadd[8];                     // pos[s]*W

    const int t = threadIdx.x;

    // Block-contiguous chunks: c_k = bid*1024 + k*256 + t, k = 0..3.
    const int cbase = blockIdx.x * (4 * NTHR) + t;
    const int c0 = cbase, c1 = cbase + NTHR, c2 = cbase + 2 * NTHR, c3 = cbase + 3 * NTHR;
    const int row0 = c0 >> 3, sub0 = c0 & 7;
    const int row1 = c1 >> 3, sub1 = c1 & 7;
    const int row2 = c2 >> 3, sub2 = c2 & 7;
    const int row3 = c3 >> 3, sub3 = c3 & 7;

    // ---- issue ALL x loads FIRST (latency hides under setup) ----
    const float* xb0 = x + (size_t)row0 * 96 + sub0 * 4;
    const float* xb1 = x + (size_t)row1 * 96 + sub1 * 4;
    const float* xb2 = x + (size_t)row2 * 96 + sub2 * 4;
    const float* xb3 = x + (size_t)row3 * 96 + sub3 * 4;
    float4 a0 = *(const float4*)(xb0), a1 = *(const float4*)(xb0 + 32), a2 = *(const float4*)(xb0 + 64);
    float4 b0 = *(const float4*)(xb1), b1 = *(const float4*)(xb1 + 32), b2 = *(const float4*)(xb1 + 64);
    float4 d0 = *(const float4*)(xb2), d1 = *(const float4*)(xb2 + 32), d2 = *(const float4*)(xb2 + 64);
    float4 e0 = *(const float4*)(xb3), e1 = *(const float4*)(xb3 + 32), e2 = *(const float4*)(xb3 + 64);

    // ---- parallel setup: col[e] = sum_n Wv[n,e] ----
    const float4* Wv4 = (const float4*)Wv;          // [96 rows][24 slots]
    if (t < 192) {
        const int slot = t % 24;
        const int g    = t / 24;                    // 0..7, 12 rows each
        const int n0   = g * 12;
        float4 s = Wv4[n0 * 24 + slot];
        #pragma unroll
        for (int n = 1; n < 12; ++n) {
            float4 q = Wv4[(n0 + n) * 24 + slot];
            s.x += q.x; s.y += q.y; s.z += q.z; s.w += q.w;
        }
        part[g][slot] = s;
    } else if (t < 200) {
        const int s = t - 192;
        float p = bp[s];
        #pragma unroll
        for (int j = 1; j < 8; ++j) p += (float)j * Wp[s * 8 + j];
        posv[s] = p;
    }
    __syncthreads();
    if (t < 32) {
        float4 cc = make_float4(0.f, 0.f, 0.f, 0.f);
        if (t < 24) {
            cc = part[0][t];
            #pragma unroll
            for (int g = 1; g < 8; ++g) {
                float4 q = part[g][t];
                cc.x += q.x; cc.y += q.y; cc.z += q.z; cc.w += q.w;
            }
            col4[t] = cc;
        }
        float w = cc.x + cc.y + cc.z + cc.w;
        w += __shfl_xor(w, 16, 32);
        w += __shfl_xor(w,  8, 32);
        w += __shfl_xor(w,  4, 32);
        w += __shfl_xor(w,  2, 32);
        w += __shfl_xor(w,  1, 32);
        if (t < 8) rowadd[t] = posv[t] * w;
    }
    __syncthreads();

#define DO_CHUNK(A0, A1, A2, ROW, SUB)                                          \
    {                                                                           \
        float4 w0 = col4[(SUB) + 0], w1 = col4[(SUB) + 8], w2 = col4[(SUB) + 16]; \
        float dot = A0.x * w0.x + A0.y * w0.y + A0.z * w0.z + A0.w * w0.w       \
                  + A1.x * w1.x + A1.y * w1.y + A1.z * w1.z + A1.w * w1.w       \
                  + A2.x * w2.x + A2.y * w2.y + A2.z * w2.z + A2.w * w2.w;      \
        dot += __shfl_xor(dot, 1);                                              \
        dot += __shfl_xor(dot, 2);                                              \
        dot += __shfl_xor(dot, 4);                                              \
        const float val = dot + rowadd[(ROW) & 7];                              \
        float4 v = make_float4(val, val, val, val);                             \
        float* ob = out + (size_t)(ROW) * 96 + (SUB) * 4;                       \
        *(float4*)(ob)      = v;                                                \
        *(float4*)(ob + 32) = v;                                                \
        *(float4*)(ob + 64) = v;                                                \
    }

    DO_CHUNK(a0, a1, a2, row0, sub0)
    DO_CHUNK(b0, b1, b2, row1, sub1)
    DO_CHUNK(d0, d1, d2, row2, sub2)
    DO_CHUNK(e0, e1, e2, row3, sub3)
#undef DO_CHUNK
}

extern "C" void kernel_launch(void* const* d_in, const int* in_sizes, int n_in,
                              void* d_out, int out_size, void* d_ws, size_t ws_size,
                              hipStream_t stream) {
    const float* x  = (const float*)d_in[0];
    const float* Wp = (const float*)d_in[1];
    const float* bp = (const float*)d_in[2];
    const float* Wv = (const float*)d_in[3];
    // Wk (d_in[4]) and Wq (d_in[5]) cancel out of the math entirely.
    float* out = (float*)d_out;

    attn_fused_kernel<<<NBLK, NTHR, 0, stream>>>(x, Wp, bp, Wv, out);
}